// Round 6
// baseline (234.793 us; speedup 1.0000x reference)
//
#include <hip/hip_runtime.h>

#define N_NODES 50000
#define N_EDGES 800000
#define IN_CH 128
#define HID 64
#define HID2 32
#define BN_EPS 1e-5f

// ---------- degree + per-edge rank (one atomic pass, coalesced rank store) ----------
__global__ __launch_bounds__(256) void k_degrank(const int* __restrict__ ei, int* __restrict__ deg,
                                                 int* __restrict__ rank, int E) {
    int t = blockIdx.x * 256 + threadIdx.x;
    int e = t * 4;
    if (e >= E) return;
    int4 c4 = *(const int4*)(ei + E + e);
    int4 rk;
    rk.x = atomicAdd(&deg[c4.x], 1);
    rk.y = atomicAdd(&deg[c4.y], 1);
    rk.z = atomicAdd(&deg[c4.z], 1);
    rk.w = atomicAdd(&deg[c4.w], 1);
    *(int4*)(rank + e) = rk;
}

// ---------- scan stage 1 (block sums) + dinv ----------
__global__ __launch_bounds__(256) void k_scan1(const int* __restrict__ deg, int* __restrict__ bsum,
                                               float* __restrict__ dinv, int N) {
    __shared__ int s[256];
    int i = blockIdx.x * 256 + threadIdx.x;
    int d = (i < N) ? deg[i] : 0;
    if (i < N) dinv[i] = rsqrtf((float)d + 1.0f);  // +1 = self loop
    s[threadIdx.x] = d;
    __syncthreads();
    for (int off = 128; off > 0; off >>= 1) {
        if (threadIdx.x < off) s[threadIdx.x] += s[threadIdx.x + off];
        __syncthreads();
    }
    if (threadIdx.x == 0) bsum[blockIdx.x] = s[0];
}

__global__ __launch_bounds__(256) void k_scan2(const int* __restrict__ bsum, int* __restrict__ bofs,
                                               int* __restrict__ offs, int NB, int N) {
    __shared__ int s[256];
    int t = threadIdx.x;
    int v = (t < NB) ? bsum[t] : 0;
    s[t] = v; __syncthreads();
    for (int off = 1; off < 256; off <<= 1) {
        int u = (t >= off) ? s[t - off] : 0;
        __syncthreads(); s[t] += u; __syncthreads();
    }
    if (t < NB) bofs[t] = s[t] - v;          // exclusive
    if (t == NB - 1) offs[N] = s[t];         // total == E
}

__global__ __launch_bounds__(256) void k_scan3(const int* __restrict__ deg, const int* __restrict__ bofs,
                                               int* __restrict__ offs, int N) {
    __shared__ int s[256];
    int i = blockIdx.x * 256 + threadIdx.x, t = threadIdx.x;
    int v = (i < N) ? deg[i] : 0;
    s[t] = v; __syncthreads();
    for (int off = 1; off < 256; off <<= 1) {
        int u = (t >= off) ? s[t - off] : 0;
        __syncthreads(); s[t] += u; __syncthreads();
    }
    if (i < N) offs[i] = bofs[blockIdx.x] + s[t] - v;
}

// ---------- CSR fill, atomic-free: csr[offs[c]+rank[e]] = row (ushort: N<65536) ----------
__global__ __launch_bounds__(256) void k_fillr(const int* __restrict__ ei, const int* __restrict__ rank,
                                               const int* __restrict__ offs, unsigned short* __restrict__ csr, int E) {
    int t = blockIdx.x * 256 + threadIdx.x;
    int e = t * 4;
    if (e >= E) return;
    int4 r4 = *(const int4*)(ei + e);
    int4 c4 = *(const int4*)(ei + E + e);
    int4 k4 = *(const int4*)(rank + e);
    csr[offs[c4.x] + k4.x] = (unsigned short)r4.x;
    csr[offs[c4.y] + k4.y] = (unsigned short)r4.y;
    csr[offs[c4.z] + k4.z] = (unsigned short)r4.z;
    csr[offs[c4.w] + k4.w] = (unsigned short)r4.w;
}

// ---------- LDS-tiled GEMM: outp[n][f] = dinv[n] * sum_k in[n][k]*W[k][f] ----------
template <int BM, int KD, int FD, int AS>
__global__ __launch_bounds__(256) void k_gemm(const float* __restrict__ in, const float* __restrict__ W,
                                              const float* __restrict__ dinv, float* __restrict__ outp, int N) {
    __shared__ float As[BM * AS];
    __shared__ float Ws[KD * FD];
    int tid = threadIdx.x;
    int n0 = blockIdx.x * BM;
    const int TOT4 = BM * KD / 4;
    const int K4 = KD / 4;
#pragma unroll
    for (int idx = tid; idx < TOT4; idx += 256) {
        int r = idx / K4, c = idx % K4;
        int n = n0 + r; if (n > N - 1) n = N - 1;
        float4 v = *(const float4*)(in + (size_t)n * KD + c * 4);
        *(float4*)(As + r * AS + c * 4) = v;
    }
    const int WT4 = KD * FD / 4;
#pragma unroll
    for (int idx = tid; idx < WT4; idx += 256) {
        *(float4*)(Ws + idx * 4) = *(const float4*)(W + idx * 4);
    }
    __syncthreads();
    const int NFG = FD / 4;
    int tn = tid % NFG, tm = tid / NFG;
    int na = tm * 4, fb = tn * 4;
    float acc[4][4] = {};
#pragma unroll 4
    for (int k = 0; k < KD; k += 4) {
        float4 a[4], b[4];
#pragma unroll
        for (int i = 0; i < 4; ++i) a[i] = *(const float4*)(As + (na + i) * AS + k);
#pragma unroll
        for (int j = 0; j < 4; ++j) b[j] = *(const float4*)(Ws + (k + j) * FD + fb);
#pragma unroll
        for (int i = 0; i < 4; ++i) {
            acc[i][0] = fmaf(a[i].x, b[0].x, acc[i][0]);
            acc[i][1] = fmaf(a[i].x, b[0].y, acc[i][1]);
            acc[i][2] = fmaf(a[i].x, b[0].z, acc[i][2]);
            acc[i][3] = fmaf(a[i].x, b[0].w, acc[i][3]);
            acc[i][0] = fmaf(a[i].y, b[1].x, acc[i][0]);
            acc[i][1] = fmaf(a[i].y, b[1].y, acc[i][1]);
            acc[i][2] = fmaf(a[i].y, b[1].z, acc[i][2]);
            acc[i][3] = fmaf(a[i].y, b[1].w, acc[i][3]);
            acc[i][0] = fmaf(a[i].z, b[2].x, acc[i][0]);
            acc[i][1] = fmaf(a[i].z, b[2].y, acc[i][1]);
            acc[i][2] = fmaf(a[i].z, b[2].z, acc[i][2]);
            acc[i][3] = fmaf(a[i].z, b[2].w, acc[i][3]);
            acc[i][0] = fmaf(a[i].w, b[3].x, acc[i][0]);
            acc[i][1] = fmaf(a[i].w, b[3].y, acc[i][1]);
            acc[i][2] = fmaf(a[i].w, b[3].z, acc[i][2]);
            acc[i][3] = fmaf(a[i].w, b[3].w, acc[i][3]);
        }
    }
#pragma unroll
    for (int i = 0; i < 4; ++i) {
        int n = n0 + na + i;
        if (n < N) {
            float dn = dinv[n];
            float4 o = make_float4(acc[i][0] * dn, acc[i][1] * dn, acc[i][2] * dn, acc[i][3] * dn);
            *(float4*)(outp + (size_t)n * FD + fb) = o;
        }
    }
}

// ---------- gather layer 1: ONE node per wave, lane = feature (64) ----------
// No intra-wave degree divergence; edge loop runs exactly deg(n) (+<=7 tail).
__global__ __launch_bounds__(256) void k_gather1(const float* __restrict__ h1p, const int* __restrict__ offs,
                                                 const unsigned short* __restrict__ csr, const float* __restrict__ dinv,
                                                 const float* __restrict__ b1, const float* __restrict__ g1,
                                                 const float* __restrict__ be1, const float* __restrict__ rm1,
                                                 const float* __restrict__ rv1, float* __restrict__ hact, int N) {
    int w = (blockIdx.x * 256 + threadIdx.x) >> 6;      // node id (wave-uniform)
    int lane = threadIdx.x & 63;                        // feature
    if (w >= N) return;
    int start = offs[w], end = offs[w + 1];
    float acc = h1p[((size_t)w << 6) + lane];           // self loop
    for (int j = start; j < end; j += 64) {
        int rid = (j + lane < end) ? (int)csr[j + lane] : 0;
        int cnt = end - j; if (cnt > 64) cnt = 64;
        int t = 0;
        for (; t + 7 < cnt; t += 8) {
            int r0 = __shfl(rid, t + 0, 64), r1 = __shfl(rid, t + 1, 64);
            int r2 = __shfl(rid, t + 2, 64), r3 = __shfl(rid, t + 3, 64);
            int r4 = __shfl(rid, t + 4, 64), r5 = __shfl(rid, t + 5, 64);
            int r6 = __shfl(rid, t + 6, 64), r7 = __shfl(rid, t + 7, 64);
            float a0 = h1p[((size_t)r0 << 6) + lane];
            float a1 = h1p[((size_t)r1 << 6) + lane];
            float a2 = h1p[((size_t)r2 << 6) + lane];
            float a3 = h1p[((size_t)r3 << 6) + lane];
            float a4 = h1p[((size_t)r4 << 6) + lane];
            float a5 = h1p[((size_t)r5 << 6) + lane];
            float a6 = h1p[((size_t)r6 << 6) + lane];
            float a7 = h1p[((size_t)r7 << 6) + lane];
            acc += ((a0 + a1) + (a2 + a3)) + ((a4 + a5) + (a6 + a7));
        }
        for (; t < cnt; ++t) {
            int r = __shfl(rid, t, 64);
            acc += h1p[((size_t)r << 6) + lane];
        }
    }
    float v = dinv[w] * acc + b1[lane];
    v = (v - rm1[lane]) * (g1[lane] * rsqrtf(rv1[lane] + BN_EPS)) + be1[lane];
    hact[((size_t)w << 6) + lane] = fmaxf(v, 0.f);
}

// ---------- gather layer 2: ONE node per 32-lane half, lane = feature + fused FC ----------
__global__ __launch_bounds__(256) void k_gather2(const float* __restrict__ h2p, const int* __restrict__ offs,
                                                 const unsigned short* __restrict__ csr, const float* __restrict__ dinv,
                                                 const float* __restrict__ b2, const float* __restrict__ g2,
                                                 const float* __restrict__ be2, const float* __restrict__ rm2,
                                                 const float* __restrict__ rv2, const float* __restrict__ fcW,
                                                 const float* __restrict__ fcb, float* __restrict__ out, int N) {
    int idx = blockIdx.x * 256 + threadIdx.x;
    int w = idx >> 5;                                   // node id (half-wave uniform)
    int l = idx & 31;                                   // feature
    if (w >= N) return;
    int sb = (threadIdx.x >> 5 & 1) << 5;               // 0 or 32: this half's base lane
    int start = offs[w], end = offs[w + 1];
    float acc = h2p[((size_t)w << 5) + l];              // self loop
    for (int j = start; j < end; j += 32) {
        int rid = (j + l < end) ? (int)csr[j + l] : 0;
        int cnt = end - j; if (cnt > 32) cnt = 32;
        int t = 0;
        for (; t + 7 < cnt; t += 8) {
            int r0 = __shfl(rid, sb + t + 0, 64), r1 = __shfl(rid, sb + t + 1, 64);
            int r2 = __shfl(rid, sb + t + 2, 64), r3 = __shfl(rid, sb + t + 3, 64);
            int r4 = __shfl(rid, sb + t + 4, 64), r5 = __shfl(rid, sb + t + 5, 64);
            int r6 = __shfl(rid, sb + t + 6, 64), r7 = __shfl(rid, sb + t + 7, 64);
            float a0 = h2p[((size_t)r0 << 5) + l];
            float a1 = h2p[((size_t)r1 << 5) + l];
            float a2 = h2p[((size_t)r2 << 5) + l];
            float a3 = h2p[((size_t)r3 << 5) + l];
            float a4 = h2p[((size_t)r4 << 5) + l];
            float a5 = h2p[((size_t)r5 << 5) + l];
            float a6 = h2p[((size_t)r6 << 5) + l];
            float a7 = h2p[((size_t)r7 << 5) + l];
            acc += ((a0 + a1) + (a2 + a3)) + ((a4 + a5) + (a6 + a7));
        }
        for (; t < cnt; ++t) {
            int r = __shfl(rid, sb + t, 64);
            acc += h2p[((size_t)r << 5) + l];
        }
    }
    float v = dinv[w] * acc + b2[l];
    v = (v - rm2[l]) * (g2[l] * rsqrtf(rv2[l] + BN_EPS)) + be2[l];
    float s = fmaxf(v, 0.f) * fcW[l];
#pragma unroll
    for (int o = 16; o > 0; o >>= 1) s += __shfl_down(s, o, 32);
    if (l == 0) out[w] = s + fcb[0];
}

extern "C" void kernel_launch(void* const* d_in, const int* in_sizes, int n_in,
                              void* d_out, int out_size, void* d_ws, size_t ws_size,
                              hipStream_t stream) {
    const float* x   = (const float*)d_in[0];
    const int*   ei  = (const int*)d_in[1];
    const float* W1  = (const float*)d_in[2];
    const float* b1  = (const float*)d_in[3];
    const float* W2  = (const float*)d_in[4];
    const float* b2  = (const float*)d_in[5];
    const float* fcW = (const float*)d_in[6];
    const float* fcb = (const float*)d_in[7];
    const float* g1  = (const float*)d_in[8];
    const float* be1 = (const float*)d_in[9];
    const float* rm1 = (const float*)d_in[10];
    const float* rv1 = (const float*)d_in[11];
    const float* g2  = (const float*)d_in[12];
    const float* be2 = (const float*)d_in[13];
    const float* rm2 = (const float*)d_in[14];
    const float* rv2 = (const float*)d_in[15];
    float* out = (float*)d_out;

    const int N = N_NODES, E = N_EDGES;
    const int NB = (N + 255) / 256;          // 196 scan blocks

    char* base = (char*)d_ws;
    int*            deg  = (int*)(base);                 // N ints
    int*            offs = (int*)(base + 200704);        // N+1 ints
    float*          dinv = (float*)(base + 401408);      // N floats
    int*            bsum = (int*)(base + 602112);        // 256 ints
    int*            bofs = (int*)(base + 603136);        // 256 ints
    int*            rank = (int*)(base + 604160);        // E ints (3.2 MB)
    unsigned short* csr  = (unsigned short*)(base + 3804160); // E ushort (1.6 MB)
    float*          h1p  = (float*)(base + 5404160);     // N*64 (12.8 MB)
    float*          hact = (float*)(base + 18204160);    // N*64 (12.8 MB)
    float*          h2p  = h1p;   // h1p dead after gather1

    hipMemsetAsync(deg, 0, (size_t)N * sizeof(int), stream);

    k_degrank<<<(E / 4 + 255) / 256, 256, 0, stream>>>(ei, deg, rank, E);
    k_scan1<<<NB, 256, 0, stream>>>(deg, bsum, dinv, N);
    k_scan2<<<1, 256, 0, stream>>>(bsum, bofs, offs, NB, N);
    k_scan3<<<NB, 256, 0, stream>>>(deg, bofs, offs, N);
    k_fillr<<<(E / 4 + 255) / 256, 256, 0, stream>>>(ei, rank, offs, csr, E);

    // Layer 1: BM=64, K=128, F=64, A-stride 132
    k_gemm<64, IN_CH, HID, 132><<<(N + 63) / 64, 256, 0, stream>>>(x, W1, dinv, h1p, N);
    k_gather1<<<((size_t)N * 64 + 255) / 256, 256, 0, stream>>>(h1p, offs, csr, dinv, b1, g1, be1, rm1, rv1, hact, N);
    // Layer 2: BM=128, K=64, F=32, A-stride 68
    k_gemm<128, HID, HID2, 68><<<(N + 127) / 128, 256, 0, stream>>>(hact, W2, dinv, h2p, N);
    k_gather2<<<((size_t)N * 32 + 255) / 256, 256, 0, stream>>>(h2p, offs, csr, dinv, b2, g2, be2, rm2, rv2, fcW, fcb, out, N);
}